// Round 15
// baseline (507.906 us; speedup 1.0000x reference)
//
#include <hip/hip_runtime.h>
#include <hip/hip_bf16.h>

typedef __bf16 bf16_t;
typedef __bf16 bf16x8 __attribute__((ext_vector_type(8)));
typedef __bf16 bf16x4 __attribute__((ext_vector_type(4)));
typedef float f32x4 __attribute__((ext_vector_type(4)));

static constexpr int E = 1024;
static constexpr int BROWS = 16384;
static constexpr size_t MB = 1ull << 20;

__device__ __forceinline__ float gelu_f(float x) {
  float t = __expf(-x * fmaf(0.0713548163f, x * x, 1.5957691216f));
  return x / (1.0f + t);
}

// ---------------- f32 -> bf16 convert ----------------
__global__ __launch_bounds__(256) void cvt_f32_bf16(const float* __restrict__ src,
                                                    bf16_t* __restrict__ dst, int n4) {
  int stride = gridDim.x * blockDim.x;
  for (int i = blockIdx.x * blockDim.x + threadIdx.x; i < n4; i += stride) {
    float4 v = reinterpret_cast<const float4*>(src)[i];
    bf16x4 o;
    o[0] = (bf16_t)v.x; o[1] = (bf16_t)v.y; o[2] = (bf16_t)v.z; o[3] = (bf16_t)v.w;
    reinterpret_cast<bf16x4*>(dst)[i] = o;
  }
}

// ---------------- batched f32 -> bf16 convert (two tensors) ----------------
__global__ __launch_bounds__(256) void cvt2_f32_bf16(const float* __restrict__ s1,
                                                     bf16_t* __restrict__ d1,
                                                     const float* __restrict__ s2,
                                                     bf16_t* __restrict__ d2, int n4) {
  int stride = gridDim.x * blockDim.x;
  for (int i = blockIdx.x * blockDim.x + threadIdx.x; i < 2 * n4; i += stride) {
    const float* src = (i < n4) ? s1 : s2;
    bf16_t* dst = (i < n4) ? d1 : d2;
    int k = (i < n4) ? i : i - n4;
    float4 v = reinterpret_cast<const float4*>(src)[k];
    bf16x4 o;
    o[0] = (bf16_t)v.x; o[1] = (bf16_t)v.y; o[2] = (bf16_t)v.z; o[3] = (bf16_t)v.w;
    reinterpret_cast<bf16x4*>(dst)[k] = o;
  }
}

// ---------------- batched f32 -> bf16 transposed convert (two 1024x1024) ----------------
__global__ __launch_bounds__(256) void cvt_transpose2(const float* __restrict__ in1,
                                                      bf16_t* __restrict__ out1,
                                                      const float* __restrict__ in2,
                                                      bf16_t* __restrict__ out2) {
  const float* in = blockIdx.z ? in2 : in1;
  bf16_t* out = blockIdx.z ? out2 : out1;
  __shared__ float t[64][65];
  const int bx = blockIdx.x * 64, by = blockIdx.y * 64;
  const int tid = threadIdx.x;
  const int r = tid >> 2, c4 = (tid & 3) * 16;
#pragma unroll
  for (int j = 0; j < 4; ++j) {
    float4 v = *reinterpret_cast<const float4*>(&in[(long)(by + r) * E + bx + c4 + j * 4]);
    t[r][c4 + j * 4 + 0] = v.x;
    t[r][c4 + j * 4 + 1] = v.y;
    t[r][c4 + j * 4 + 2] = v.z;
    t[r][c4 + j * 4 + 3] = v.w;
  }
  __syncthreads();
#pragma unroll
  for (int j = 0; j < 16; j += 4) {
    bf16x4 o;
    o[0] = (bf16_t)t[c4 + j + 0][r];
    o[1] = (bf16_t)t[c4 + j + 1][r];
    o[2] = (bf16_t)t[c4 + j + 2][r];
    o[3] = (bf16_t)t[c4 + j + 3][r];
    *reinterpret_cast<bf16x4*>(&out[(long)(bx + r) * E + by + c4 + j]) = o;
  }
}

// ---------------- batched fused bias (both attention branches) ----------------
__global__ __launch_bounds__(256) void fuse_bias2(const float* __restrict__ wo1,
                                                  const float* __restrict__ bv1,
                                                  const float* __restrict__ bo1,
                                                  float* __restrict__ out1,
                                                  const float* __restrict__ wo2,
                                                  const float* __restrict__ bv2,
                                                  const float* __restrict__ bo2,
                                                  float* __restrict__ out2) {
  const int gr = (blockIdx.x * 256 + threadIdx.x) >> 6;
  const int lane = threadIdx.x & 63;
  const int row = gr & 1023;
  const float* wo = (gr < 1024) ? wo1 : wo2;
  const float* bv = (gr < 1024) ? bv1 : bv2;
  const float* bo = (gr < 1024) ? bo1 : bo2;
  float* outb = (gr < 1024) ? out1 : out2;
  float s = 0.f;
  for (int k = lane; k < E; k += 64) s += wo[(long)row * E + k] * bv[k];
#pragma unroll
  for (int off = 32; off; off >>= 1) s += __shfl_down(s, off);
  if (lane == 0) outb[row] = s + bo[row];
}

// ---------------- batched small bf16 GEMM: both Wc = wo @ wv (128 blocks) ----------------
__global__ __launch_bounds__(256) void gemm_small2(const bf16_t* __restrict__ A1,
                                                   const bf16_t* __restrict__ B1,
                                                   bf16_t* __restrict__ C1,
                                                   const bf16_t* __restrict__ A2,
                                                   const bf16_t* __restrict__ B2,
                                                   bf16_t* __restrict__ C2) {
  const int K = 1024, N = 1024;
  const int orig = blockIdx.x;
  const int wgid = (orig & 7) * 16 + (orig >> 3);
  const int bx = wgid & 7;
  const int byy = wgid >> 3;
  const bf16_t* A = (byy < 8) ? A1 : A2;
  const bf16_t* Bw = (byy < 8) ? B1 : B2;
  bf16_t* Cout = (byy < 8) ? C1 : C2;
  const int by = byy & 7;
  __shared__ bf16_t As[128 * 32];
  __shared__ bf16_t Bs[128 * 32];
  const int tid = threadIdx.x;
  const int lane = tid & 63;
  const int w = tid >> 6;
  const int wr = w >> 1, wc = w & 1;
  const long m0 = (long)by * 128;
  const long n0 = (long)bx * 128;
  const bf16_t* aSrc = A + (m0 + (tid >> 2)) * (long)K + (tid & 3) * 8;
  const bf16_t* bSrc = Bw + (n0 + (tid >> 2)) * (long)K + (tid & 3) * 8;
  f32x4 acc[4][4];
#pragma unroll
  for (int mi = 0; mi < 4; ++mi)
#pragma unroll
    for (int ni = 0; ni < 4; ++ni) acc[mi][ni] = {0.f, 0.f, 0.f, 0.f};
  const int nkt = K >> 5;
  for (int kt = 0; kt < nkt; ++kt) {
#pragma unroll
    for (int r = 0; r < 2; ++r) {
      __builtin_amdgcn_global_load_lds(
          (__attribute__((address_space(1))) void*)(aSrc + (long)r * 64 * K + kt * 32),
          (__attribute__((address_space(3))) void*)((char*)As + r * 4096 + w * 1024), 16, 0, 0);
      __builtin_amdgcn_global_load_lds(
          (__attribute__((address_space(1))) void*)(bSrc + (long)r * 64 * K + kt * 32),
          (__attribute__((address_space(3))) void*)((char*)Bs + r * 4096 + w * 1024), 16, 0, 0);
    }
    __syncthreads();
    bf16x8 af[4], bfv[4];
#pragma unroll
    for (int i = 0; i < 4; ++i) {
      af[i] = *reinterpret_cast<const bf16x8*>(
          &As[(wr * 64 + i * 16 + (lane & 15)) * 32 + (lane >> 4) * 8]);
      bfv[i] = *reinterpret_cast<const bf16x8*>(
          &Bs[(wc * 64 + i * 16 + (lane & 15)) * 32 + (lane >> 4) * 8]);
    }
#pragma unroll
    for (int mi = 0; mi < 4; ++mi)
#pragma unroll
      for (int ni = 0; ni < 4; ++ni)
        acc[mi][ni] = __builtin_amdgcn_mfma_f32_16x16x32_bf16(af[mi], bfv[ni], acc[mi][ni], 0, 0, 0);
    __syncthreads();
  }
  const long crow0 = m0 + wr * 64 + ((lane >> 4) * 4);
  const long ccol0 = n0 + wc * 64 + (lane & 15);
#pragma unroll
  for (int mi = 0; mi < 4; ++mi)
#pragma unroll
    for (int ni = 0; ni < 4; ++ni)
#pragma unroll
      for (int r = 0; r < 4; ++r)
        Cout[(crow0 + mi * 16 + r) * N + ccol0 + ni * 16] = (bf16_t)acc[mi][ni][r];
}

// ============ 128x256 tile, 8 waves (2x4), ring-3 counted-vmcnt bf16 GEMM ============
// (R12-proven, 166us on G5.) 2 blocks/CU (72 KB LDS). Stage slot j+2 during iter j;
// steady vmcnt(3) certifies slot j+1 before the barrier; R5-verified swizzle.
#define GLDS1(gp, lp)                                                             \
  __builtin_amdgcn_global_load_lds((__attribute__((address_space(1))) void*)(gp), \
                                   (__attribute__((address_space(3))) void*)(lp), 16, 0, 0)

template <int ACT_GELU, int OUT_BF16>
__global__ __launch_bounds__(512, 4) void gemm128(const bf16_t* __restrict__ A,
                                                  const bf16_t* __restrict__ Bw,
                                                  const float* __restrict__ bias,
                                                  void* __restrict__ Cout, int K, int N,
                                                  int NBX) {
  __shared__ char smem[73728];  // 3 slots x (A 8KB + B 16KB)
  const int nwg = gridDim.x;
  const int orig = blockIdx.x;
  const int q = nwg >> 3;
  const int wgid = (orig & 7) * q + (orig >> 3);  // bijective for nwg%8==0
  const int bx = wgid % NBX;
  const int by = wgid / NBX;
  const long m0 = (long)by * 128;
  const long n0 = (long)bx * 256;

  const int tid = threadIdx.x;
  const int lane = tid & 63;
  const int w = tid >> 6;
  const int wr = w >> 2;
  const int wc = w & 3;

  const int sv = (lane & 7) ^ (lane >> 3);
  const int r2 = (lane >> 3) * 2 + (sv >> 2);
  const int kc = (sv & 3) * 8;
  const bf16_t* srcA = A + (m0 + w * 16 + r2) * (long)K + kc;
  const bf16_t* srcB0 = Bw + (n0 + w * 32 + r2) * (long)K + kc;
  const bf16_t* srcB1 = srcB0 + 16 * (long)K;

#define STAGE1(s, t)                                   \
  {                                                    \
    char* sd = smem + (s) * 24576;                     \
    const long tt = (long)(t) * 32;                    \
    GLDS1(srcA + tt, sd + w * 1024);                   \
    GLDS1(srcB0 + tt, sd + 8192 + w * 2048);           \
    GLDS1(srcB1 + tt, sd + 8192 + w * 2048 + 1024);    \
  }

  const int laneoff =
      ((lane >> 1) & 7) * 128 +
      ((((((lane & 1) << 2) | (lane >> 4))) ^ ((lane >> 1) & 7)) << 4);
  const int wrOff = wr * 4096;
  const int wcOff = wc * 4096;

  f32x4 acc[4][4];
#pragma unroll
  for (int mi = 0; mi < 4; ++mi)
#pragma unroll
    for (int ni = 0; ni < 4; ++ni) acc[mi][ni] = {0.f, 0.f, 0.f, 0.f};

  STAGE1(0, 0);
  STAGE1(1, 1);
  asm volatile("s_waitcnt vmcnt(3)" ::: "memory");
  asm volatile("s_barrier" ::: "memory");

  const int NS = K >> 5;
  int cur = 0;
#pragma unroll 1
  for (int j = 0; j < NS; ++j) {
    const char* sb = smem + cur * 24576;
    if (j + 2 < NS) {
      int nx = cur + 2;
      if (nx >= 3) nx -= 3;
      STAGE1(nx, j + 2);
    }
    bf16x8 a[4], b[4];
#pragma unroll
    for (int i = 0; i < 4; ++i)
      a[i] = *reinterpret_cast<const bf16x8*>(sb + wrOff + i * 1024 + laneoff);
#pragma unroll
    for (int i = 0; i < 4; ++i)
      b[i] = *reinterpret_cast<const bf16x8*>(sb + 8192 + wcOff + i * 1024 + laneoff);
    __builtin_amdgcn_s_setprio(1);
#pragma unroll
    for (int mi = 0; mi < 4; ++mi)
#pragma unroll
      for (int ni = 0; ni < 4; ++ni)
        acc[mi][ni] = __builtin_amdgcn_mfma_f32_16x16x32_bf16(a[mi], b[ni], acc[mi][ni], 0, 0, 0);
    __builtin_amdgcn_s_setprio(0);
    if (j + 1 < NS) {
      asm volatile("s_waitcnt lgkmcnt(0)" ::: "memory");
      if (j + 2 < NS)
        asm volatile("s_waitcnt vmcnt(3)" ::: "memory");
      else
        asm volatile("s_waitcnt vmcnt(0)" ::: "memory");
      asm volatile("s_barrier" ::: "memory");
    }
    cur = (cur + 1 == 3) ? 0 : cur + 1;
  }

  float bv[4];
#pragma unroll
  for (int ni = 0; ni < 4; ++ni) bv[ni] = bias[n0 + wc * 64 + ni * 16 + (lane & 15)];
  const long crow0 = m0 + wr * 64 + ((lane >> 4) * 4);
  const long ccol0 = n0 + wc * 64 + (lane & 15);
#pragma unroll
  for (int mi = 0; mi < 4; ++mi) {
#pragma unroll
    for (int ni = 0; ni < 4; ++ni) {
#pragma unroll
      for (int rr = 0; rr < 4; ++rr) {
        float v = acc[mi][ni][rr] + bv[ni];
        if (ACT_GELU) v = gelu_f(v);
        long idx = (crow0 + mi * 16 + rr) * N + ccol0 + ni * 16;
        if (OUT_BF16)
          ((bf16_t*)Cout)[idx] = (bf16_t)v;
        else
          ((float*)Cout)[idx] = v;
      }
    }
  }
#undef STAGE1
}
#undef GLDS1

// ============ 256x256, BK=64, 8 waves, 4-quadrant-phase bf16 GEMM (R14-proven) ============
#define GLDS(gp, lp)                                                              \
  __builtin_amdgcn_global_load_lds((__attribute__((address_space(1))) void*)(gp), \
                                   (__attribute__((address_space(3))) void*)(lp), 16, 0, 0)

template <int ACT_GELU, int OUT_BF16>
__global__ __launch_bounds__(512) void gemm256b(const bf16_t* __restrict__ A,
                                                const bf16_t* __restrict__ Bw,
                                                const float* __restrict__ bias,
                                                void* __restrict__ Cout, int K, int N,
                                                int NBX) {
  __shared__ char smem[131072];
  const int nwg = gridDim.x;
  const int orig = blockIdx.x;
  const int q = nwg >> 3;
  const int wgid = (orig & 7) * q + (orig >> 3);
  const int bx = wgid % NBX;
  const int by = wgid / NBX;
  const long m0 = (long)by * 256;
  const long n0 = (long)bx * 256;

  const int tid = threadIdx.x;
  const int lane = tid & 63;
  const int w = tid >> 6;
  const int wr = w >> 2;
  const int wc = w & 3;

  const bf16_t* srcA = A + m0 * (long)K;
  const bf16_t* srcB = Bw + n0 * (long)K;
  const long koff = ((lane & 7) ^ (lane >> 3)) * 8;
  const long srow = (long)(w * 8 + (lane >> 3));

#define STAGE(SEL, h, t)                                                            \
  {                                                                                 \
    const bf16_t* _s = (SEL) ? srcB : srcA;                                         \
    char* _d = smem + ((t)&1) * 65536 + (SEL)*32768 + (h)*16384 + w * 1024 + lane * 16; \
    const long _r = (long)((h)*128) + srow;                                         \
    GLDS(_s + _r * (long)K + (long)(t)*64 + koff, _d);                              \
    GLDS(_s + (_r + 64) * (long)K + (long)(t)*64 + koff, _d + 8192);                \
  }

  const int xr = lane & 7;
  const int o16 = lane >> 4;
  const int sA0 = ((o16) ^ xr) << 4;
  const int sA1 = ((4 + o16) ^ xr) << 4;
  const int l15 = lane & 15;
  const int aRow = l15 * 128;
  const int bHalf = 32768 + (wc >> 1) * 16384;
  const int bRow = ((wc & 1) * 64 + l15) * 128;

#define RD_A(dst, db, qm)                                                              \
  _Pragma("unroll") for (int mi = 0; mi < 4; ++mi) {                                   \
    dst[mi * 2 + 0] = *reinterpret_cast<const bf16x8*>(                                \
        smem + (db) + wr * 16384 + (qm)*8192 + mi * 2048 + aRow + sA0);                \
    dst[mi * 2 + 1] = *reinterpret_cast<const bf16x8*>(                                \
        smem + (db) + wr * 16384 + (qm)*8192 + mi * 2048 + aRow + sA1);                \
  }
#define RD_B(dst, db, qn)                                                              \
  _Pragma("unroll") for (int nj = 0; nj < 2; ++nj) {                                   \
    dst[nj * 2 + 0] = *reinterpret_cast<const bf16x8*>(                                \
        smem + (db) + bHalf + (qn)*4096 + nj * 2048 + bRow + sA0);                     \
    dst[nj * 2 + 1] = *reinterpret_cast<const bf16x8*>(                                \
        smem + (db) + bHalf + (qn)*4096 + nj * 2048 + bRow + sA1);                     \
  }
#define MM(QM, QN, AR, BR)                                                             \
  __builtin_amdgcn_s_setprio(1);                                                       \
  _Pragma("unroll") for (int mi = 0; mi < 4; ++mi)                                     \
      _Pragma("unroll") for (int nj = 0; nj < 2; ++nj)                                 \
          _Pragma("unroll") for (int kk = 0; kk < 2; ++kk)                             \
              acc[(QM)*4 + mi][(QN)*2 + nj] = __builtin_amdgcn_mfma_f32_16x16x32_bf16( \
                  AR[mi * 2 + kk], BR[nj * 2 + kk], acc[(QM)*4 + mi][(QN)*2 + nj], 0, 0, 0); \
  __builtin_amdgcn_s_setprio(0);
#define BAR asm volatile("s_barrier" ::: "memory")
#define LGKM0                                          \
  asm volatile("s_waitcnt lgkmcnt(0)" ::: "memory");   \
  __builtin_amdgcn_sched_barrier(0)

  f32x4 acc[8][4];
#pragma unroll
  for (int mi = 0; mi < 8; ++mi)
#pragma unroll
    for (int ni = 0; ni < 4; ++ni) acc[mi][ni] = {0.f, 0.f, 0.f, 0.f};

  const int NT = K >> 6;
  STAGE(0, 0, 0); STAGE(0, 1, 0); STAGE(1, 0, 0); STAGE(1, 1, 0);
  STAGE(0, 0, 1); STAGE(0, 1, 1);
  asm volatile("s_waitcnt vmcnt(4)" ::: "memory");
  BAR;

  bf16x8 aE[8], aO[8], bE[4], bO[4];
#pragma unroll 1
  for (int t = 0; t < NT; ++t) {
    const int db = (t & 1) * 65536;
    RD_A(aE, db, 0);
    RD_B(bE, db, 0);
    if (t + 1 < NT) { STAGE(1, 0, t + 1); STAGE(1, 1, t + 1); }
    BAR; LGKM0;
    MM(0, 0, aE, bE);
    BAR;
    RD_B(bO, db, 1);
    BAR; LGKM0;
    MM(0, 1, aE, bO);
    BAR;
    RD_A(aO, db, 1);
    BAR; LGKM0;
    MM(1, 1, aO, bO);
    BAR;
    RD_B(bE, db, 0);
    if (t + 2 < NT) {
      STAGE(0, 0, t + 2);
      STAGE(0, 1, t + 2);
      asm volatile("s_waitcnt vmcnt(4)" ::: "memory");
    } else {
      asm volatile("s_waitcnt vmcnt(0)" ::: "memory");
    }
    BAR; LGKM0;
    MM(1, 0, aO, bE);
    BAR;
  }

  float bv[4];
#pragma unroll
  for (int ni = 0; ni < 4; ++ni) bv[ni] = bias[n0 + wc * 64 + ni * 16 + (lane & 15)];
  const long crow0 = m0 + wr * 128 + ((lane >> 4) * 4);
  const long ccol0 = n0 + wc * 64 + (lane & 15);
#pragma unroll
  for (int mi = 0; mi < 8; ++mi) {
#pragma unroll
    for (int ni = 0; ni < 4; ++ni) {
#pragma unroll
      for (int rr = 0; rr < 4; ++rr) {
        float v = acc[mi][ni][rr] + bv[ni];
        if (ACT_GELU) v = gelu_f(v);
        long idx = (crow0 + mi * 16 + rr) * N + ccol0 + ni * 16;
        if (OUT_BF16)
          ((bf16_t*)Cout)[idx] = (bf16_t)v;
        else
          ((float*)Cout)[idx] = v;
      }
    }
  }
#undef STAGE
#undef RD_A
#undef RD_B
#undef MM
#undef BAR
#undef LGKM0
}
#undef GLDS

// ---------------- fused residual-add + LayerNorm ----------------
template <int MODE>
__global__ __launch_bounds__(256) void ln_k(const float* __restrict__ Xf,
                                            const bf16_t* __restrict__ Xb,
                                            const float* __restrict__ Yf,
                                            const bf16_t* __restrict__ Yb,
                                            const float* __restrict__ gamma,
                                            const float* __restrict__ beta,
                                            const bf16_t* __restrict__ addB,
                                            float* __restrict__ outF,
                                            bf16_t* __restrict__ outB) {
  const int tid = threadIdx.x;
  const long base = (long)blockIdx.x * E;
  float4 s;
  if (MODE < 2) {
    float4 xv = reinterpret_cast<const float4*>(Xf + base)[tid];
    bf16x4 yv = reinterpret_cast<const bf16x4*>(Yb + base)[tid];
    s.x = xv.x + (float)yv[0]; s.y = xv.y + (float)yv[1];
    s.z = xv.z + (float)yv[2]; s.w = xv.w + (float)yv[3];
  } else {
    bf16x4 xv = reinterpret_cast<const bf16x4*>(Xb + base)[tid];
    float4 yv = reinterpret_cast<const float4*>(Yf + base)[tid];
    s.x = (float)xv[0] + yv.x; s.y = (float)xv[1] + yv.y;
    s.z = (float)xv[2] + yv.z; s.w = (float)xv[3] + yv.w;
  }
  float sum = s.x + s.y + s.z + s.w;
  float sq = s.x * s.x + s.y * s.y + s.z * s.z + s.w * s.w;
#pragma unroll
  for (int off = 32; off > 0; off >>= 1) {
    sum += __shfl_down(sum, off);
    sq += __shfl_down(sq, off);
  }
  __shared__ float red[2][4];
  const int w = tid >> 6;
  if ((tid & 63) == 0) { red[0][w] = sum; red[1][w] = sq; }
  __syncthreads();
  float tot = red[0][0] + red[0][1] + red[0][2] + red[0][3];
  float tsq = red[1][0] + red[1][1] + red[1][2] + red[1][3];
  const float mu = tot * (1.0f / E);
  const float var = tsq * (1.0f / E) - mu * mu;
  const float rs = rsqrtf(var + 1e-5f);
  float4 gv = reinterpret_cast<const float4*>(gamma)[tid];
  float4 bvv = reinterpret_cast<const float4*>(beta)[tid];
  float4 o;
  o.x = (s.x - mu) * rs * gv.x + bvv.x;
  o.y = (s.y - mu) * rs * gv.y + bvv.y;
  o.z = (s.z - mu) * rs * gv.z + bvv.z;
  o.w = (s.w - mu) * rs * gv.w + bvv.w;
  if (MODE == 1) {
    bf16x4 av = reinterpret_cast<const bf16x4*>(addB + base)[tid];
    o.x += (float)av[0]; o.y += (float)av[1]; o.z += (float)av[2]; o.w += (float)av[3];
  }
  if (MODE == 2) {
    reinterpret_cast<float4*>(outF + base)[tid] = o;
  } else {
    bf16x4 ob;
    ob[0] = (bf16_t)o.x; ob[1] = (bf16_t)o.y; ob[2] = (bf16_t)o.z; ob[3] = (bf16_t)o.w;
    reinterpret_cast<bf16x4*>(outB + base)[tid] = ob;
  }
}

extern "C" void kernel_launch(void* const* d_in, const int* in_sizes, int n_in, void* d_out,
                              int out_size, void* d_ws, size_t ws_size, hipStream_t stream) {
  const float* img_feat = (const float*)d_in[0];
  const float* txt_feat = (const float*)d_in[1];
  const float* w_in1 = (const float*)d_in[2];
  const float* b_in1 = (const float*)d_in[3];
  const float* w_out1 = (const float*)d_in[4];
  const float* b_out1 = (const float*)d_in[5];
  const float* w_in2 = (const float*)d_in[6];
  const float* b_in2 = (const float*)d_in[7];
  const float* w_out2 = (const float*)d_in[8];
  const float* b_out2 = (const float*)d_in[9];
  const float* g1 = (const float*)d_in[10];
  const float* be1 = (const float*)d_in[11];
  const float* g2 = (const float*)d_in[12];
  const float* be2 = (const float*)d_in[13];
  const float* g3 = (const float*)d_in[14];
  const float* be3 = (const float*)d_in[15];
  const float* w_ffn1 = (const float*)d_in[16];
  const float* b_ffn1 = (const float*)d_in[17];
  const float* w_ffn2 = (const float*)d_in[18];
  const float* b_ffn2 = (const float*)d_in[19];

  if (ws_size < 184 * MB) return;
  char* ws = (char*)d_ws;
  bf16_t* TXTB = (bf16_t*)(ws + 0 * MB);
  bf16_t* ATT = (bf16_t*)(ws + 32 * MB);
  bf16_t* IMGB = (bf16_t*)(ws + 64 * MB);
  bf16_t* T0a = (bf16_t*)(ws + 64 * MB);   // transients (dead before LN1 writes IMGB)
  bf16_t* T0b = (bf16_t*)(ws + 66 * MB);
  bf16_t* T1a = (bf16_t*)(ws + 68 * MB);
  bf16_t* T1b = (bf16_t*)(ws + 70 * MB);
  bf16_t* H = (bf16_t*)(ws + 0 * MB);
  bf16_t* COMB = (bf16_t*)(ws + 128 * MB);
  bf16_t* Wc1 = (bf16_t*)(ws + 160 * MB);
  bf16_t* Wc2 = (bf16_t*)(ws + 162 * MB);
  bf16_t* wf1b = (bf16_t*)(ws + 164 * MB);
  bf16_t* wf2b = (bf16_t*)(ws + 172 * MB);
  float* bias1 = (float*)d_out;
  float* bias2 = bias1 + E;

  dim3 blk(256);
  dim3 blk512(512);
  cvt_f32_bf16<<<dim3(2048), blk, 0, stream>>>(txt_feat, TXTB, BROWS * E / 4);
  cvt2_f32_bf16<<<dim3(2048), blk, 0, stream>>>(w_ffn1, wf1b, w_ffn2, wf2b, 4 * E * E / 4);

  // prep: Wc1 = wo1 @ wv1, Wc2 = wo2 @ wv2, fused biases (batched)
  cvt_transpose2<<<dim3(16, 16, 2), blk, 0, stream>>>(w_in1 + 2 * E * E, T0a,
                                                      w_in2 + 2 * E * E, T0b);
  cvt2_f32_bf16<<<dim3(1024), blk, 0, stream>>>(w_out1, T1a, w_out2, T1b, E * E / 4);
  gemm_small2<<<dim3(128), blk, 0, stream>>>(T1a, T0a, Wc1, T1b, T0b, Wc2);
  fuse_bias2<<<dim3(512), blk, 0, stream>>>(w_out1, b_in1 + 2 * E, b_out1, bias1,
                                            w_out2, b_in2 + 2 * E, b_out2, bias2);

  // G12: att1 = txt @ Wc1^T + bias1   (gemm256b, 64 x 4 = 256 blocks)
  gemm256b<0, 1><<<dim3(256), blk512, 0, stream>>>(TXTB, Wc1, bias1, ATT, E, E, 4);
  // LN1: img = LN(img_feat + att1)
  ln_k<0><<<dim3(BROWS), blk, 0, stream>>>(img_feat, nullptr, nullptr, ATT, g1, be1, nullptr,
                                           nullptr, IMGB);
  // G34: att2 = img @ Wc2^T + bias2
  gemm256b<0, 1><<<dim3(256), blk512, 0, stream>>>(IMGB, Wc2, bias2, ATT, E, E, 4);
  // LN2: comb = img + LN(txt_feat + att2)
  ln_k<1><<<dim3(BROWS), blk, 0, stream>>>(txt_feat, nullptr, nullptr, ATT, g2, be2, IMGB,
                                           nullptr, COMB);
  // G5: h = gelu(comb @ wf1^T + b_ffn1)   (gemm128 ring-3, 128 x 16 = 2048 blocks)
  gemm128<1, 1><<<dim3(2048), blk512, 0, stream>>>(COMB, wf1b, b_ffn1, H, E, 4 * E, 16);
  // G6: ffn = h @ wf2^T + b_ffn2 -> d_out (f32)   (gemm256b, 64 x 4 = 256 blocks, K=4096)
  gemm256b<0, 0><<<dim3(256), blk512, 0, stream>>>(H, wf2b, b_ffn2, d_out, 4 * E, E, 4);
  // LN3: out = LN(comb + ffn), in place on d_out
  ln_k<2><<<dim3(BROWS), blk, 0, stream>>>(nullptr, COMB, (float*)d_out, nullptr, g3, be3,
                                           nullptr, (float*)d_out, nullptr);
}

// Round 16
// 498.678 us; speedup vs baseline: 1.0185x; 1.0185x over previous
//
#include <hip/hip_runtime.h>
#include <hip/hip_bf16.h>

typedef __bf16 bf16_t;
typedef __bf16 bf16x8 __attribute__((ext_vector_type(8)));
typedef __bf16 bf16x4 __attribute__((ext_vector_type(4)));
typedef float f32x4 __attribute__((ext_vector_type(4)));

static constexpr int E = 1024;
static constexpr int BROWS = 16384;
static constexpr size_t MB = 1ull << 20;

__device__ __forceinline__ float gelu_f(float x) {
  float t = __expf(-x * fmaf(0.0713548163f, x * x, 1.5957691216f));
  return x / (1.0f + t);
}

// ---------------- f32 -> bf16 convert ----------------
__global__ __launch_bounds__(256) void cvt_f32_bf16(const float* __restrict__ src,
                                                    bf16_t* __restrict__ dst, int n4) {
  int stride = gridDim.x * blockDim.x;
  for (int i = blockIdx.x * blockDim.x + threadIdx.x; i < n4; i += stride) {
    float4 v = reinterpret_cast<const float4*>(src)[i];
    bf16x4 o;
    o[0] = (bf16_t)v.x; o[1] = (bf16_t)v.y; o[2] = (bf16_t)v.z; o[3] = (bf16_t)v.w;
    reinterpret_cast<bf16x4*>(dst)[i] = o;
  }
}

// ---------------- batched f32 -> bf16 convert (two tensors) ----------------
__global__ __launch_bounds__(256) void cvt2_f32_bf16(const float* __restrict__ s1,
                                                     bf16_t* __restrict__ d1,
                                                     const float* __restrict__ s2,
                                                     bf16_t* __restrict__ d2, int n4) {
  int stride = gridDim.x * blockDim.x;
  for (int i = blockIdx.x * blockDim.x + threadIdx.x; i < 2 * n4; i += stride) {
    const float* src = (i < n4) ? s1 : s2;
    bf16_t* dst = (i < n4) ? d1 : d2;
    int k = (i < n4) ? i : i - n4;
    float4 v = reinterpret_cast<const float4*>(src)[k];
    bf16x4 o;
    o[0] = (bf16_t)v.x; o[1] = (bf16_t)v.y; o[2] = (bf16_t)v.z; o[3] = (bf16_t)v.w;
    reinterpret_cast<bf16x4*>(dst)[k] = o;
  }
}

// ---------------- batched f32 -> bf16 transposed convert (two 1024x1024) ----------------
__global__ __launch_bounds__(256) void cvt_transpose2(const float* __restrict__ in1,
                                                      bf16_t* __restrict__ out1,
                                                      const float* __restrict__ in2,
                                                      bf16_t* __restrict__ out2) {
  const float* in = blockIdx.z ? in2 : in1;
  bf16_t* out = blockIdx.z ? out2 : out1;
  __shared__ float t[64][65];
  const int bx = blockIdx.x * 64, by = blockIdx.y * 64;
  const int tid = threadIdx.x;
  const int r = tid >> 2, c4 = (tid & 3) * 16;
#pragma unroll
  for (int j = 0; j < 4; ++j) {
    float4 v = *reinterpret_cast<const float4*>(&in[(long)(by + r) * E + bx + c4 + j * 4]);
    t[r][c4 + j * 4 + 0] = v.x;
    t[r][c4 + j * 4 + 1] = v.y;
    t[r][c4 + j * 4 + 2] = v.z;
    t[r][c4 + j * 4 + 3] = v.w;
  }
  __syncthreads();
#pragma unroll
  for (int j = 0; j < 16; j += 4) {
    bf16x4 o;
    o[0] = (bf16_t)t[c4 + j + 0][r];
    o[1] = (bf16_t)t[c4 + j + 1][r];
    o[2] = (bf16_t)t[c4 + j + 2][r];
    o[3] = (bf16_t)t[c4 + j + 3][r];
    *reinterpret_cast<bf16x4*>(&out[(long)(bx + r) * E + by + c4 + j]) = o;
  }
}

// ---------------- batched fused bias (both attention branches) ----------------
__global__ __launch_bounds__(256) void fuse_bias2(const float* __restrict__ wo1,
                                                  const float* __restrict__ bv1,
                                                  const float* __restrict__ bo1,
                                                  float* __restrict__ out1,
                                                  const float* __restrict__ wo2,
                                                  const float* __restrict__ bv2,
                                                  const float* __restrict__ bo2,
                                                  float* __restrict__ out2) {
  const int gr = (blockIdx.x * 256 + threadIdx.x) >> 6;
  const int lane = threadIdx.x & 63;
  const int row = gr & 1023;
  const float* wo = (gr < 1024) ? wo1 : wo2;
  const float* bv = (gr < 1024) ? bv1 : bv2;
  const float* bo = (gr < 1024) ? bo1 : bo2;
  float* outb = (gr < 1024) ? out1 : out2;
  float s = 0.f;
  for (int k = lane; k < E; k += 64) s += wo[(long)row * E + k] * bv[k];
#pragma unroll
  for (int off = 32; off; off >>= 1) s += __shfl_down(s, off);
  if (lane == 0) outb[row] = s + bo[row];
}

// ---------------- batched small bf16 GEMM: both Wc = wo @ wv (128 blocks) ----------------
__global__ __launch_bounds__(256) void gemm_small2(const bf16_t* __restrict__ A1,
                                                   const bf16_t* __restrict__ B1,
                                                   bf16_t* __restrict__ C1,
                                                   const bf16_t* __restrict__ A2,
                                                   const bf16_t* __restrict__ B2,
                                                   bf16_t* __restrict__ C2) {
  const int K = 1024, N = 1024;
  const int orig = blockIdx.x;
  const int wgid = (orig & 7) * 16 + (orig >> 3);
  const int bx = wgid & 7;
  const int byy = wgid >> 3;
  const bf16_t* A = (byy < 8) ? A1 : A2;
  const bf16_t* Bw = (byy < 8) ? B1 : B2;
  bf16_t* Cout = (byy < 8) ? C1 : C2;
  const int by = byy & 7;
  __shared__ bf16_t As[128 * 32];
  __shared__ bf16_t Bs[128 * 32];
  const int tid = threadIdx.x;
  const int lane = tid & 63;
  const int w = tid >> 6;
  const int wr = w >> 1, wc = w & 1;
  const long m0 = (long)by * 128;
  const long n0 = (long)bx * 128;
  const bf16_t* aSrc = A + (m0 + (tid >> 2)) * (long)K + (tid & 3) * 8;
  const bf16_t* bSrc = Bw + (n0 + (tid >> 2)) * (long)K + (tid & 3) * 8;
  f32x4 acc[4][4];
#pragma unroll
  for (int mi = 0; mi < 4; ++mi)
#pragma unroll
    for (int ni = 0; ni < 4; ++ni) acc[mi][ni] = {0.f, 0.f, 0.f, 0.f};
  const int nkt = K >> 5;
  for (int kt = 0; kt < nkt; ++kt) {
#pragma unroll
    for (int r = 0; r < 2; ++r) {
      __builtin_amdgcn_global_load_lds(
          (__attribute__((address_space(1))) void*)(aSrc + (long)r * 64 * K + kt * 32),
          (__attribute__((address_space(3))) void*)((char*)As + r * 4096 + w * 1024), 16, 0, 0);
      __builtin_amdgcn_global_load_lds(
          (__attribute__((address_space(1))) void*)(bSrc + (long)r * 64 * K + kt * 32),
          (__attribute__((address_space(3))) void*)((char*)Bs + r * 4096 + w * 1024), 16, 0, 0);
    }
    __syncthreads();
    bf16x8 af[4], bfv[4];
#pragma unroll
    for (int i = 0; i < 4; ++i) {
      af[i] = *reinterpret_cast<const bf16x8*>(
          &As[(wr * 64 + i * 16 + (lane & 15)) * 32 + (lane >> 4) * 8]);
      bfv[i] = *reinterpret_cast<const bf16x8*>(
          &Bs[(wc * 64 + i * 16 + (lane & 15)) * 32 + (lane >> 4) * 8]);
    }
#pragma unroll
    for (int mi = 0; mi < 4; ++mi)
#pragma unroll
      for (int ni = 0; ni < 4; ++ni)
        acc[mi][ni] = __builtin_amdgcn_mfma_f32_16x16x32_bf16(af[mi], bfv[ni], acc[mi][ni], 0, 0, 0);
    __syncthreads();
  }
  const long crow0 = m0 + wr * 64 + ((lane >> 4) * 4);
  const long ccol0 = n0 + wc * 64 + (lane & 15);
#pragma unroll
  for (int mi = 0; mi < 4; ++mi)
#pragma unroll
    for (int ni = 0; ni < 4; ++ni)
#pragma unroll
      for (int r = 0; r < 4; ++r)
        Cout[(crow0 + mi * 16 + r) * N + ccol0 + ni * 16] = (bf16_t)acc[mi][ni][r];
}

// ============ 256x256, BK=64, 8 waves, 4-quadrant-phase m201-class bf16 GEMM ============
// LDS 128KB: dbuf(t&1) x {A-half0,A-half1,B-half0,B-half1} x 16KB. Octet-XOR swizzle:
// row r, octet o at byte r*128 + ((o^(r&7))<<4); staging uses inverse-permuted global src.
// Per tile t, 4 phases = C-quadrants (0,0),(0,1),(1,1),(1,0):
//   q0: rd Am0(8)+Bn0(4); stage B0,B1(t+1); bar; lgkm0; 16 MFMA; bar
//   q1: rd Bn1(4);                          bar; lgkm0; 16 MFMA; bar
//   q2: rd Am1(8);                          bar; lgkm0; 16 MFMA; bar
//   q3: rd Bn0(4); stage A0,A1(t+2); vmcnt(4); bar; lgkm0; 16 MFMA; bar
// A(t+2) staged at q3 only (after q2's last A reads of this dbuf — WAR-safe).
// vmcnt(4) at q3: newest 4 = A(t+2); completes B(t+1) + A(t+1) -> tile t+1 certified.
#define GLDS(gp, lp)                                                              \
  __builtin_amdgcn_global_load_lds((__attribute__((address_space(1))) void*)(gp), \
                                   (__attribute__((address_space(3))) void*)(lp), 16, 0, 0)

template <int ACT_GELU, int OUT_BF16>
__global__ __launch_bounds__(512) void gemm256b(const bf16_t* __restrict__ A,
                                                const bf16_t* __restrict__ Bw,
                                                const float* __restrict__ bias,
                                                void* __restrict__ Cout, int K, int N,
                                                int NBX) {
  __shared__ char smem[131072];
  const int nwg = gridDim.x;
  const int orig = blockIdx.x;
  const int q = nwg >> 3;
  const int wgid = (orig & 7) * q + (orig >> 3);  // bijective for nwg%8==0
  const int bx = wgid % NBX;
  const int by = wgid / NBX;
  const long m0 = (long)by * 256;
  const long n0 = (long)bx * 256;

  const int tid = threadIdx.x;
  const int lane = tid & 63;
  const int w = tid >> 6;   // 8 waves
  const int wr = w >> 2;    // 0..1: rows wr*128
  const int wc = w & 3;     // 0..3: cols wc*64

  const bf16_t* srcA = A + m0 * (long)K;
  const bf16_t* srcB = Bw + n0 * (long)K;
  const long koff = ((lane & 7) ^ (lane >> 3)) * 8;   // inverse-swizzled k-octet
  const long srow = (long)(w * 8 + (lane >> 3));      // staging row within 64-row group

#define STAGE(SEL, h, t)                                                            \
  {                                                                                 \
    const bf16_t* _s = (SEL) ? srcB : srcA;                                         \
    char* _d = smem + ((t)&1) * 65536 + (SEL)*32768 + (h)*16384 + w * 1024 + lane * 16; \
    const long _r = (long)((h)*128) + srow;                                         \
    GLDS(_s + _r * (long)K + (long)(t)*64 + koff, _d);                              \
    GLDS(_s + (_r + 64) * (long)K + (long)(t)*64 + koff, _d + 8192);                \
  }

  const int xr = lane & 7;
  const int o16 = lane >> 4;                 // 0..3
  const int sA0 = ((o16) ^ xr) << 4;         // kk=0 octets 0..3
  const int sA1 = ((4 + o16) ^ xr) << 4;     // kk=1 octets 4..7
  const int l15 = lane & 15;
  const int aRow = l15 * 128;                // + mi*2048 (+qm*8192)
  const int bHalf = 32768 + (wc >> 1) * 16384;
  const int bRow = ((wc & 1) * 64 + l15) * 128;  // + nj*2048 (+qn*4096)

#define RD_A(dst, db, qm)                                                              \
  _Pragma("unroll") for (int mi = 0; mi < 4; ++mi) {                                   \
    dst[mi * 2 + 0] = *reinterpret_cast<const bf16x8*>(                                \
        smem + (db) + wr * 16384 + (qm)*8192 + mi * 2048 + aRow + sA0);                \
    dst[mi * 2 + 1] = *reinterpret_cast<const bf16x8*>(                                \
        smem + (db) + wr * 16384 + (qm)*8192 + mi * 2048 + aRow + sA1);                \
  }
#define RD_B(dst, db, qn)                                                              \
  _Pragma("unroll") for (int nj = 0; nj < 2; ++nj) {                                   \
    dst[nj * 2 + 0] = *reinterpret_cast<const bf16x8*>(                                \
        smem + (db) + bHalf + (qn)*4096 + nj * 2048 + bRow + sA0);                     \
    dst[nj * 2 + 1] = *reinterpret_cast<const bf16x8*>(                                \
        smem + (db) + bHalf + (qn)*4096 + nj * 2048 + bRow + sA1);                     \
  }
#define MM(QM, QN, AR, BR)                                                             \
  __builtin_amdgcn_s_setprio(1);                                                       \
  _Pragma("unroll") for (int mi = 0; mi < 4; ++mi)                                     \
      _Pragma("unroll") for (int nj = 0; nj < 2; ++nj)                                 \
          _Pragma("unroll") for (int kk = 0; kk < 2; ++kk)                             \
              acc[(QM)*4 + mi][(QN)*2 + nj] = __builtin_amdgcn_mfma_f32_16x16x32_bf16( \
                  AR[mi * 2 + kk], BR[nj * 2 + kk], acc[(QM)*4 + mi][(QN)*2 + nj], 0, 0, 0); \
  __builtin_amdgcn_s_setprio(0);
#define BAR asm volatile("s_barrier" ::: "memory")
#define LGKM0                                          \
  asm volatile("s_waitcnt lgkmcnt(0)" ::: "memory");   \
  __builtin_amdgcn_sched_barrier(0)

  f32x4 acc[8][4];
#pragma unroll
  for (int mi = 0; mi < 8; ++mi)
#pragma unroll
    for (int ni = 0; ni < 4; ++ni) acc[mi][ni] = {0.f, 0.f, 0.f, 0.f};

  const int NT = K >> 6;
  // prologue: t0 full + A0(1),A1(1)  (12 loads); certify t0 (oldest 8) -> vmcnt(4)
  STAGE(0, 0, 0); STAGE(0, 1, 0); STAGE(1, 0, 0); STAGE(1, 1, 0);
  STAGE(0, 0, 1); STAGE(0, 1, 1);
  asm volatile("s_waitcnt vmcnt(4)" ::: "memory");
  BAR;

  bf16x8 aE[8], aO[8], bE[4], bO[4];
#pragma unroll 1
  for (int t = 0; t < NT; ++t) {
    const int db = (t & 1) * 65536;
    // ---- q0: quadrant (0,0); stage next tile's B ----
    RD_A(aE, db, 0);
    RD_B(bE, db, 0);
    if (t + 1 < NT) { STAGE(1, 0, t + 1); STAGE(1, 1, t + 1); }
    BAR; LGKM0;
    MM(0, 0, aE, bE);
    BAR;
    // ---- q1: quadrant (0,1) ----
    RD_B(bO, db, 1);
    BAR; LGKM0;
    MM(0, 1, aE, bO);
    BAR;
    // ---- q2: quadrant (1,1) — last A reads of this dbuf ----
    RD_A(aO, db, 1);
    BAR; LGKM0;
    MM(1, 1, aO, bO);
    BAR;
    // ---- q3: quadrant (1,0); stage A(t+2) (safe: A reads ended q2); certify t+1 ----
    RD_B(bE, db, 0);
    if (t + 2 < NT) {
      STAGE(0, 0, t + 2);
      STAGE(0, 1, t + 2);
      asm volatile("s_waitcnt vmcnt(4)" ::: "memory");
    } else {
      asm volatile("s_waitcnt vmcnt(0)" ::: "memory");
    }
    BAR; LGKM0;
    MM(1, 0, aO, bE);
    BAR;
  }

  // ---- epilogue: bias + (gelu) + direct store (R5-proven C/D layout) ----
  float bv[4];
#pragma unroll
  for (int ni = 0; ni < 4; ++ni) bv[ni] = bias[n0 + wc * 64 + ni * 16 + (lane & 15)];
  const long crow0 = m0 + wr * 128 + ((lane >> 4) * 4);
  const long ccol0 = n0 + wc * 64 + (lane & 15);
#pragma unroll
  for (int mi = 0; mi < 8; ++mi) {
#pragma unroll
    for (int ni = 0; ni < 4; ++ni) {
#pragma unroll
      for (int rr = 0; rr < 4; ++rr) {
        float v = acc[mi][ni][rr] + bv[ni];
        if (ACT_GELU) v = gelu_f(v);
        long idx = (crow0 + mi * 16 + rr) * N + ccol0 + ni * 16;
        if (OUT_BF16)
          ((bf16_t*)Cout)[idx] = (bf16_t)v;
        else
          ((float*)Cout)[idx] = v;
      }
    }
  }
#undef STAGE
#undef RD_A
#undef RD_B
#undef MM
#undef BAR
#undef LGKM0
}
#undef GLDS

// ---------------- fused residual-add + LayerNorm ----------------
template <int MODE>
__global__ __launch_bounds__(256) void ln_k(const float* __restrict__ Xf,
                                            const bf16_t* __restrict__ Xb,
                                            const float* __restrict__ Yf,
                                            const bf16_t* __restrict__ Yb,
                                            const float* __restrict__ gamma,
                                            const float* __restrict__ beta,
                                            const bf16_t* __restrict__ addB,
                                            float* __restrict__ outF,
                                            bf16_t* __restrict__ outB) {
  const int tid = threadIdx.x;
  const long base = (long)blockIdx.x * E;
  float4 s;
  if (MODE < 2) {
    float4 xv = reinterpret_cast<const float4*>(Xf + base)[tid];
    bf16x4 yv = reinterpret_cast<const bf16x4*>(Yb + base)[tid];
    s.x = xv.x + (float)yv[0]; s.y = xv.y + (float)yv[1];
    s.z = xv.z + (float)yv[2]; s.w = xv.w + (float)yv[3];
  } else {
    bf16x4 xv = reinterpret_cast<const bf16x4*>(Xb + base)[tid];
    float4 yv = reinterpret_cast<const float4*>(Yf + base)[tid];
    s.x = (float)xv[0] + yv.x; s.y = (float)xv[1] + yv.y;
    s.z = (float)xv[2] + yv.z; s.w = (float)xv[3] + yv.w;
  }
  float sum = s.x + s.y + s.z + s.w;
  float sq = s.x * s.x + s.y * s.y + s.z * s.z + s.w * s.w;
#pragma unroll
  for (int off = 32; off > 0; off >>= 1) {
    sum += __shfl_down(sum, off);
    sq += __shfl_down(sq, off);
  }
  __shared__ float red[2][4];
  const int w = tid >> 6;
  if ((tid & 63) == 0) { red[0][w] = sum; red[1][w] = sq; }
  __syncthreads();
  float tot = red[0][0] + red[0][1] + red[0][2] + red[0][3];
  float tsq = red[1][0] + red[1][1] + red[1][2] + red[1][3];
  const float mu = tot * (1.0f / E);
  const float var = tsq * (1.0f / E) - mu * mu;
  const float rs = rsqrtf(var + 1e-5f);
  float4 gv = reinterpret_cast<const float4*>(gamma)[tid];
  float4 bvv = reinterpret_cast<const float4*>(beta)[tid];
  float4 o;
  o.x = (s.x - mu) * rs * gv.x + bvv.x;
  o.y = (s.y - mu) * rs * gv.y + bvv.y;
  o.z = (s.z - mu) * rs * gv.z + bvv.z;
  o.w = (s.w - mu) * rs * gv.w + bvv.w;
  if (MODE == 1) {
    bf16x4 av = reinterpret_cast<const bf16x4*>(addB + base)[tid];
    o.x += (float)av[0]; o.y += (float)av[1]; o.z += (float)av[2]; o.w += (float)av[3];
  }
  if (MODE == 2) {
    reinterpret_cast<float4*>(outF + base)[tid] = o;
  } else {
    bf16x4 ob;
    ob[0] = (bf16_t)o.x; ob[1] = (bf16_t)o.y; ob[2] = (bf16_t)o.z; ob[3] = (bf16_t)o.w;
    reinterpret_cast<bf16x4*>(outB + base)[tid] = ob;
  }
}

extern "C" void kernel_launch(void* const* d_in, const int* in_sizes, int n_in, void* d_out,
                              int out_size, void* d_ws, size_t ws_size, hipStream_t stream) {
  const float* img_feat = (const float*)d_in[0];
  const float* txt_feat = (const float*)d_in[1];
  const float* w_in1 = (const float*)d_in[2];
  const float* b_in1 = (const float*)d_in[3];
  const float* w_out1 = (const float*)d_in[4];
  const float* b_out1 = (const float*)d_in[5];
  const float* w_in2 = (const float*)d_in[6];
  const float* b_in2 = (const float*)d_in[7];
  const float* w_out2 = (const float*)d_in[8];
  const float* b_out2 = (const float*)d_in[9];
  const float* g1 = (const float*)d_in[10];
  const float* be1 = (const float*)d_in[11];
  const float* g2 = (const float*)d_in[12];
  const float* be2 = (const float*)d_in[13];
  const float* g3 = (const float*)d_in[14];
  const float* be3 = (const float*)d_in[15];
  const float* w_ffn1 = (const float*)d_in[16];
  const float* b_ffn1 = (const float*)d_in[17];
  const float* w_ffn2 = (const float*)d_in[18];
  const float* b_ffn2 = (const float*)d_in[19];

  if (ws_size < 184 * MB) return;
  char* ws = (char*)d_ws;
  bf16_t* TXTB = (bf16_t*)(ws + 0 * MB);
  bf16_t* ATT = (bf16_t*)(ws + 32 * MB);
  bf16_t* IMGB = (bf16_t*)(ws + 64 * MB);
  bf16_t* T0a = (bf16_t*)(ws + 64 * MB);   // transients (dead before LN1 writes IMGB)
  bf16_t* T0b = (bf16_t*)(ws + 66 * MB);
  bf16_t* T1a = (bf16_t*)(ws + 68 * MB);
  bf16_t* T1b = (bf16_t*)(ws + 70 * MB);
  bf16_t* H = (bf16_t*)(ws + 0 * MB);
  bf16_t* COMB = (bf16_t*)(ws + 128 * MB);
  bf16_t* Wc1 = (bf16_t*)(ws + 160 * MB);
  bf16_t* Wc2 = (bf16_t*)(ws + 162 * MB);
  bf16_t* wf1b = (bf16_t*)(ws + 164 * MB);
  bf16_t* wf2b = (bf16_t*)(ws + 172 * MB);
  float* bias1 = (float*)d_out;
  float* bias2 = bias1 + E;

  dim3 blk(256);
  dim3 blk512(512);
  cvt_f32_bf16<<<dim3(2048), blk, 0, stream>>>(txt_feat, TXTB, BROWS * E / 4);
  cvt2_f32_bf16<<<dim3(2048), blk, 0, stream>>>(w_ffn1, wf1b, w_ffn2, wf2b, 4 * E * E / 4);

  // prep: Wc1 = wo1 @ wv1, Wc2 = wo2 @ wv2, fused biases (batched)
  cvt_transpose2<<<dim3(16, 16, 2), blk, 0, stream>>>(w_in1 + 2 * E * E, T0a,
                                                      w_in2 + 2 * E * E, T0b);
  cvt2_f32_bf16<<<dim3(1024), blk, 0, stream>>>(w_out1, T1a, w_out2, T1b, E * E / 4);
  gemm_small2<<<dim3(128), blk, 0, stream>>>(T1a, T0a, Wc1, T1b, T0b, Wc2);
  fuse_bias2<<<dim3(512), blk, 0, stream>>>(w_out1, b_in1 + 2 * E, b_out1, bias1,
                                            w_out2, b_in2 + 2 * E, b_out2, bias2);

  // G12: att1 = txt @ Wc1^T + bias1   (64 x 4 = 256 blocks)
  gemm256b<0, 1><<<dim3(256), blk512, 0, stream>>>(TXTB, Wc1, bias1, ATT, E, E, 4);
  // LN1: img = LN(img_feat + att1)
  ln_k<0><<<dim3(BROWS), blk, 0, stream>>>(img_feat, nullptr, nullptr, ATT, g1, be1, nullptr,
                                           nullptr, IMGB);
  // G34: att2 = img @ Wc2^T + bias2
  gemm256b<0, 1><<<dim3(256), blk512, 0, stream>>>(IMGB, Wc2, bias2, ATT, E, E, 4);
  // LN2: comb = img + LN(txt_feat + att2)
  ln_k<1><<<dim3(BROWS), blk, 0, stream>>>(txt_feat, nullptr, nullptr, ATT, g2, be2, IMGB,
                                           nullptr, COMB);
  // G5: h = gelu(comb @ wf1^T + b_ffn1)   (64 x 16 = 1024 blocks)
  gemm256b<1, 1><<<dim3(1024), blk512, 0, stream>>>(COMB, wf1b, b_ffn1, H, E, 4 * E, 16);
  // G6: ffn = h @ wf2^T + b_ffn2 -> d_out (f32)   (64 x 4 = 256 blocks, K=4096)
  gemm256b<0, 0><<<dim3(256), blk512, 0, stream>>>(H, wf2b, b_ffn2, d_out, 4 * E, E, 4);
  // LN3: out = LN(comb + ffn), in place on d_out
  ln_k<2><<<dim3(BROWS), blk, 0, stream>>>(nullptr, COMB, (float*)d_out, nullptr, g3, be3,
                                           nullptr, (float*)d_out, nullptr);
}